// Round 12
// baseline (370.416 us; speedup 1.0000x reference)
//
#include <hip/hip_runtime.h>

#define D 128
#define NC 40

typedef __attribute__((ext_vector_type(8))) short short8v;
typedef __attribute__((ext_vector_type(4))) float f32x4;

__device__ __forceinline__ unsigned short f2bf(float f) {
    unsigned u = __float_as_uint(f);
    u += 0x7fff + ((u >> 16) & 1);          // RNE
    return (unsigned short)(u >> 16);
}
__device__ __forceinline__ float bf2f(unsigned short h) {
    return __uint_as_float(((unsigned)h) << 16);
}

__device__ __forceinline__ int load_idx(const int* ei, long long pos, int is64) {
    return is64 ? ei[pos * 2] : ei[pos];
}

// per-wave int64-vs-int32 detection: check high dwords of first 64 entries
__device__ __forceinline__ int detect64(const int* __restrict__ ei) {
    int lane = threadIdx.x & 63;
    int hi = ei[lane * 2 + 1];
    return __any(hi != 0) ? 0 : 1;
}

// ---------------- graph build ----------------

// count degrees (edge blocks) + convert all weights to hi/lo bf16 planes (extra blocks)
__global__ void count_convert_kernel(const int* __restrict__ ei, int* __restrict__ deg,
                                     int E, int EB,
                                     const float* __restrict__ W1, const float* __restrict__ Wh,
                                     const float* __restrict__ Wf,
                                     unsigned short* __restrict__ Wc1, unsigned short* __restrict__ Wch0,
                                     unsigned short* __restrict__ Wch1, unsigned short* __restrict__ Wcf) {
    if (blockIdx.x < EB) {
        int is64 = detect64(ei);
        int e = blockIdx.x * 256 + threadIdx.x;
        if (e < E) {
            int d = load_idx(ei, (long long)E + e, is64);   // dst
            atomicAdd(&deg[d], 1);
        }
    } else {
        int idx = (blockIdx.x - EB) * 256 + threadIdx.x;    // 0 .. 55295
        if (idx < 49152) {
            int which = idx >> 14;                           // 0,1,2
            int j = idx & 16383;
            int nn = j >> 7, k = j & 127;
            const float* W = (which == 0) ? W1 : (which == 1) ? Wh : Wh + 16384;
            unsigned short* o = (which == 0) ? Wc1 : (which == 1) ? Wch0 : Wch1;
            float v = W[k * 128 + nn];
            unsigned short h = f2bf(v);
            o[j] = h;
            o[16384 + j] = f2bf(v - bf2f(h));
        } else if (idx < 49152 + 6144) {
            int j = idx - 49152;
            int nn = j >> 7, k = j & 127;
            float v = (nn < NC) ? Wf[k * NC + nn] : 0.f;
            unsigned short h = f2bf(v);
            Wcf[j] = h;
            Wcf[6144 + j] = f2bf(v - bf2f(h));
        }
    }
}

// phase 1: per-block (512) sums of deg
__global__ void scan1_kernel(const int* __restrict__ deg, int* __restrict__ bsum, int m) {
    int i = blockIdx.x * 512 + threadIdx.x;
    int v = (i < m) ? deg[i] : 0;
    #pragma unroll
    for (int off = 32; off; off >>= 1) v += __shfl_down(v, off, 64);
    __shared__ int ws[8];
    if ((threadIdx.x & 63) == 0) ws[threadIdx.x >> 6] = v;
    __syncthreads();
    if (threadIdx.x == 0) {
        int s = 0;
        #pragma unroll
        for (int j = 0; j < 8; ++j) s += ws[j];
        bsum[blockIdx.x] = s;
    }
}

// phase 2: inline prefix over bsum + local scan + emit rowptr/fill/dinv
__global__ void scan3_kernel(const int* __restrict__ deg, const int* __restrict__ bsum,
                             int* __restrict__ rowptr, int* __restrict__ fill,
                             float* __restrict__ dinv, int n, int E, int nb) {
    int t = threadIdx.x;                       // 512
    int lane = t & 63, w = t >> 6;
    int pv = (t < nb && t < (int)blockIdx.x) ? bsum[t] : 0;
    int rs = pv;
    #pragma unroll
    for (int off = 32; off; off >>= 1) rs += __shfl_down(rs, off, 64);
    __shared__ int red[8];
    if (lane == 0) red[w] = rs;
    __syncthreads();
    int base = 0;
    #pragma unroll
    for (int j = 0; j < 8; ++j) base += red[j];
    __syncthreads();

    int i = blockIdx.x * 512 + t;
    int v = (i < n) ? deg[i] : 0;
    int s = v;
    #pragma unroll
    for (int off = 1; off < 64; off <<= 1) {
        int x = __shfl_up(s, off, 64);
        if (lane >= off) s += x;
    }
    __shared__ int wsum[8];
    if (lane == 63) wsum[w] = s;
    __syncthreads();
    int wbase = 0;
    #pragma unroll
    for (int j = 0; j < 8; ++j) if (j < w) wbase += wsum[j];
    int excl = base + wbase + s - v;
    if (i < n) {
        rowptr[i] = excl;
        fill[i]   = excl;
        dinv[i]   = rsqrtf((float)(v + 1));   // +1 self loop
    }
    if (i == 0) rowptr[n] = E;
}

// scatter edge -> CSR, packing {src, dinv[src]}
__global__ void scatter_kernel(const int* __restrict__ ei, int* __restrict__ fill,
                               const float* __restrict__ dinv, int2* __restrict__ col2, int E) {
    int is64 = detect64(ei);
    int e = blockIdx.x * 256 + threadIdx.x;
    if (e >= E) return;
    int s = load_idx(ei, (long long)e, is64);
    int d = load_idx(ei, (long long)E + e, is64);
    int pos = atomicAdd(&fill[d], 1);
    col2[pos] = make_int2(s, __float_as_int(dinv[s]));
}

// ---------------- wave-autonomous fused layer: out = relu( agg(h) @ W + b ) ----
// 256 threads = 4 INDEPENDENT waves, each owning one 16-node MFMA tile with a
// private 1KB LDS strip. No __syncthreads, no sort, no inter-wave coupling —
// r11's structure with the occupancy ceiling removed (single-wave blocks hit
// the per-CU workgroup-slot limit at 30% occupancy; 4-wave packing allows
// 8 blocks/CU = 32 waves).
__launch_bounds__(256)
__global__ void fused_wave_kernel(const float4* __restrict__ h4,
                                  const unsigned short* __restrict__ Wcvt,  // [128n][128k] hi,lo
                                  const float* __restrict__ bias,
                                  const float* __restrict__ dinv,
                                  const int* __restrict__ rowptr, const int2* __restrict__ col2,
                                  float* __restrict__ out, int n) {
    __shared__ unsigned short S[4][2][2][128];  // [wave][plane][rowpair][k], 4KB
    int t = threadIdx.x;
    int wv = t >> 6, l = t & 63;
    int p = l >> 5, li = l & 31;               // pair-node slot, lane-in-node
    int kg = l >> 4, lr = l & 15;              // MFMA k-group, row/col-in-tile
    int base = blockIdx.x * 64 + wv * 16;      // wave's first node
    if (base >= n) return;

    short8v fAh[4], fAl[4];                    // A fragments, filled across rounds
    #pragma unroll
    for (int ks = 0; ks < 4; ++ks) {
        fAh[ks] = (short8v){0,0,0,0,0,0,0,0};
        fAl[ks] = (short8v){0,0,0,0,0,0,0,0};
    }

    for (int j = 0; j < 8; ++j) {
        int node = base + 2 * j + p;
        int nd = (node < n) ? node : (n - 1);
        float dn = dinv[nd];
        size_t rowbase = (size_t)nd * 32;
        float4 hv = h4[rowbase + li];
        float4 acc;
        acc.x = hv.x * dn; acc.y = hv.y * dn; acc.z = hv.z * dn; acc.w = hv.w * dn;
        int e = rowptr[nd], e1 = rowptr[nd + 1];
        for (; e + 8 <= e1; e += 8) {
            int2 c[8];
            #pragma unroll
            for (int q = 0; q < 8; ++q) c[q] = col2[e + q];
            float4 v[8];
            #pragma unroll
            for (int q = 0; q < 8; ++q) v[q] = h4[(size_t)c[q].x * 32 + li];
            #pragma unroll
            for (int q = 0; q < 8; ++q) {
                float ds = __int_as_float(c[q].y);
                acc.x += v[q].x * ds; acc.y += v[q].y * ds;
                acc.z += v[q].z * ds; acc.w += v[q].w * ds;
            }
        }
        for (; e + 4 <= e1; e += 4) {
            int2 c[4];
            #pragma unroll
            for (int q = 0; q < 4; ++q) c[q] = col2[e + q];
            float4 v[4];
            #pragma unroll
            for (int q = 0; q < 4; ++q) v[q] = h4[(size_t)c[q].x * 32 + li];
            #pragma unroll
            for (int q = 0; q < 4; ++q) {
                float ds = __int_as_float(c[q].y);
                acc.x += v[q].x * ds; acc.y += v[q].y * ds;
                acc.z += v[q].z * ds; acc.w += v[q].w * ds;
            }
        }
        for (; e < e1; ++e) {
            int2 c = col2[e];
            float ds = __int_as_float(c.y);
            float4 v = h4[(size_t)c.x * 32 + li];
            acc.x += v.x * ds; acc.y += v.y * ds; acc.z += v.z * ds; acc.w += v.w * ds;
        }
        acc.x *= dn; acc.y *= dn; acc.z *= dn; acc.w *= dn;   // normalized aggregate

        // stage pair rows to the wave's strip as hi/lo planes
        ushort4 hi, lo;
        hi.x = f2bf(acc.x); lo.x = f2bf(acc.x - bf2f(hi.x));
        hi.y = f2bf(acc.y); lo.y = f2bf(acc.y - bf2f(hi.y));
        hi.z = f2bf(acc.z); lo.z = f2bf(acc.z - bf2f(hi.z));
        hi.w = f2bf(acc.w); lo.w = f2bf(acc.w - bf2f(hi.w));
        *(ushort4*)&S[wv][0][p][li * 4] = hi;
        *(ushort4*)&S[wv][1][p][li * 4] = lo;
        __builtin_amdgcn_wave_barrier();
        // lanes whose tile-row was produced this round pick up their A-frags
        if ((lr >> 1) == j) {
            int rp = lr & 1;
            #pragma unroll
            for (int ks = 0; ks < 4; ++ks) {
                fAh[ks] = *(short8v*)&S[wv][0][rp][ks * 32 + kg * 8];
                fAl[ks] = *(short8v*)&S[wv][1][rp][ks * 32 + kg * 8];
            }
        }
        __builtin_amdgcn_wave_barrier();
    }

    // MFMA phase: 8 n-tiles of 16 cols, B streamed from L2-hot W planes
    const unsigned short* Whi = Wcvt;
    const unsigned short* Wlo = Wcvt + 128 * 128;
    #pragma unroll
    for (int nt = 0; nt < 8; ++nt) {
        int col = nt * 16 + lr;
        short8v bh[4], bl[4];
        #pragma unroll
        for (int ks = 0; ks < 4; ++ks) {
            bh[ks] = *(const short8v*)&Whi[col * 128 + ks * 32 + kg * 8];
            bl[ks] = *(const short8v*)&Wlo[col * 128 + ks * 32 + kg * 8];
        }
        f32x4 o = (f32x4){0.f, 0.f, 0.f, 0.f};
        #pragma unroll
        for (int ks = 0; ks < 4; ++ks) {
            o = __builtin_amdgcn_mfma_f32_16x16x32_bf16(fAh[ks], bh[ks], o, 0, 0, 0);
            o = __builtin_amdgcn_mfma_f32_16x16x32_bf16(fAh[ks], bl[ks], o, 0, 0, 0);
            o = __builtin_amdgcn_mfma_f32_16x16x32_bf16(fAl[ks], bh[ks], o, 0, 0, 0);
        }
        float bv = bias[col];
        #pragma unroll
        for (int r = 0; r < 4; ++r) {
            int row = base + kg * 4 + r;     // D layout: row=(lane>>4)*4+r, col=lane&15
            if (row < n) out[(size_t)row * 128 + col] = fmaxf(o[r] + bv, 0.f);
        }
    }
}

// ---------------- MFMA final layer  C[M x 40] = A[M x 128] @ Wf + bf ----------------
__launch_bounds__(256)
__global__ void final_mfma_kernel(const float* __restrict__ A, const unsigned short* __restrict__ Wcvt,
                                  const float* __restrict__ bf, float* __restrict__ C, int M) {
    __shared__ unsigned short Ah[64 * 128];
    __shared__ unsigned short Al[64 * 128];
    int t = threadIdx.x;
    int l = t & 63, w = t >> 6;
    int lr = l & 15, lh = l >> 4;

    const unsigned short* Whi = Wcvt;            // [48n][128k]
    const unsigned short* Wlo = Wcvt + 48 * 128;
    short8v bhi[3][4], blo[3][4];
    #pragma unroll
    for (int nt = 0; nt < 3; ++nt) {
        int n = nt * 16 + lr;
        #pragma unroll
        for (int ks = 0; ks < 4; ++ks) {
            bhi[nt][ks] = *(const short8v*)&Whi[n * 128 + ks * 32 + lh * 8];
            blo[nt][ks] = *(const short8v*)&Wlo[n * 128 + ks * 32 + lh * 8];
        }
    }

    int row0 = blockIdx.x * 64;
    #pragma unroll
    for (int c = 0; c < 4; ++c) {
        int chunk = c * 256 + t;
        int r  = chunk >> 4;
        int kc = chunk & 15;
        int gr = row0 + r; if (gr >= M) gr = M - 1;
        float4 a0 = *(const float4*)&A[(size_t)gr * 128 + kc * 8];
        float4 a1 = *(const float4*)&A[(size_t)gr * 128 + kc * 8 + 4];
        float av[8] = {a0.x, a0.y, a0.z, a0.w, a1.x, a1.y, a1.z, a1.w};
        short8v hv, lv;
        #pragma unroll
        for (int j = 0; j < 8; ++j) {
            unsigned short hi = f2bf(av[j]);
            hv[j] = (short)hi;
            lv[j] = (short)f2bf(av[j] - bf2f(hi));
        }
        int off = (r << 8) + ((kc << 4) ^ ((r & 7) << 4));
        *(short8v*)((char*)Ah + off) = hv;
        *(short8v*)((char*)Al + off) = lv;
    }
    __syncthreads();

    f32x4 acc[3];
    #pragma unroll
    for (int nt = 0; nt < 3; ++nt) acc[nt] = (f32x4){0.f, 0.f, 0.f, 0.f};
    int row = w * 16 + lr;
    #pragma unroll
    for (int ks = 0; ks < 4; ++ks) {
        int off = (row << 8) + (((ks << 6) + (lh << 4)) ^ ((row & 7) << 4));
        short8v ah = *(short8v*)((char*)Ah + off);
        short8v al = *(short8v*)((char*)Al + off);
        #pragma unroll
        for (int nt = 0; nt < 3; ++nt) {
            acc[nt] = __builtin_amdgcn_mfma_f32_16x16x32_bf16(ah, bhi[nt][ks], acc[nt], 0, 0, 0);
            acc[nt] = __builtin_amdgcn_mfma_f32_16x16x32_bf16(ah, blo[nt][ks], acc[nt], 0, 0, 0);
            acc[nt] = __builtin_amdgcn_mfma_f32_16x16x32_bf16(al, bhi[nt][ks], acc[nt], 0, 0, 0);
        }
    }
    #pragma unroll
    for (int nt = 0; nt < 3; ++nt) {
        int col = nt * 16 + lr;
        #pragma unroll
        for (int r = 0; r < 4; ++r) {
            int ro = row0 + w * 16 + lh * 4 + r;
            if (col < NC && ro < M) C[(size_t)ro * NC + col] = acc[nt][r] + bf[col];
        }
    }
}

extern "C" void kernel_launch(void* const* d_in, const int* in_sizes, int n_in,
                              void* d_out, int out_size, void* d_ws, size_t ws_size,
                              hipStream_t stream) {
    const float* x  = (const float*)d_in[0];
    const int*   ei = (const int*)d_in[1];
    const float* W1 = (const float*)d_in[2];
    const float* b1 = (const float*)d_in[3];
    const float* Wh = (const float*)d_in[4];
    const float* bh = (const float*)d_in[5];
    const float* Wf = (const float*)d_in[6];
    const float* bf = (const float*)d_in[7];
    float* out = (float*)d_out;

    int n = in_sizes[0] / D;    // 50000
    int E = in_sizes[1] / 2;    // 800000

    char* ws = (char*)d_ws;
    size_t off = 0;
    auto alloc = [&](size_t bytes) {
        void* p = ws + off;
        off = (off + bytes + 255) & ~(size_t)255;
        return p;
    };
    float* B0     = (float*)alloc((size_t)n * D * 4);
    float* B1     = (float*)alloc((size_t)n * D * 4);
    int*   deg    = (int*)alloc((size_t)n * 4);
    int*   rowptr = (int*)alloc((size_t)(n + 1) * 4);
    int*   fill   = (int*)alloc((size_t)n * 4);
    int2*  col2   = (int2*)alloc((size_t)E * 8);
    float* dinv   = (float*)alloc((size_t)n * 4);
    int*   bsum   = (int*)alloc(1024 * 4);
    unsigned short* Wc1  = (unsigned short*)alloc(2 * 128 * 128 * 2);
    unsigned short* Wch0 = (unsigned short*)alloc(2 * 128 * 128 * 2);
    unsigned short* Wch1 = (unsigned short*)alloc(2 * 128 * 128 * 2);
    unsigned short* Wcf  = (unsigned short*)alloc(2 * 48 * 128 * 2);

    int EB = (E + 255) / 256;             // edge blocks
    int CB = (49152 + 6144 + 255) / 256;  // convert blocks
    int nb = (n + 511) / 512;             // 98

    hipMemsetAsync(deg, 0, (size_t)n * 4, stream);
    count_convert_kernel<<<EB + CB, 256, 0, stream>>>(ei, deg, E, EB, W1, Wh, Wf, Wc1, Wch0, Wch1, Wcf);
    scan1_kernel<<<nb, 512, 0, stream>>>(deg, bsum, n);
    scan3_kernel<<<nb, 512, 0, stream>>>(deg, bsum, rowptr, fill, dinv, n, E, nb);
    scatter_kernel<<<EB, 256, 0, stream>>>(ei, fill, dinv, col2, E);

    int fgrid = (n + 63) / 64;            // 4 waves/block, one wave per 16 nodes

    fused_wave_kernel<<<fgrid, 256, 0, stream>>>((const float4*)x, Wc1, b1, dinv, rowptr, col2, B0, n);
    fused_wave_kernel<<<fgrid, 256, 0, stream>>>((const float4*)B0, Wch0, bh, dinv, rowptr, col2, B1, n);
    fused_wave_kernel<<<fgrid, 256, 0, stream>>>((const float4*)B1, Wch1, bh + D, dinv, rowptr, col2, B0, n);
    final_mfma_kernel<<<(n + 63) / 64, 256, 0, stream>>>(B0, Wcf, bf, out, n);
}

// Round 13
// 326.062 us; speedup vs baseline: 1.1360x; 1.1360x over previous
//
#include <hip/hip_runtime.h>

#define D 128
#define NC 40

typedef __attribute__((ext_vector_type(8))) short short8v;
typedef __attribute__((ext_vector_type(4))) float f32x4;

__device__ __forceinline__ unsigned short f2bf(float f) {
    unsigned u = __float_as_uint(f);
    u += 0x7fff + ((u >> 16) & 1);          // RNE
    return (unsigned short)(u >> 16);
}
__device__ __forceinline__ float bf2f(unsigned short h) {
    return __uint_as_float(((unsigned)h) << 16);
}

__device__ __forceinline__ int load_idx(const int* ei, long long pos, int is64) {
    return is64 ? ei[pos * 2] : ei[pos];
}

// per-wave int64-vs-int32 detection: check high dwords of first 64 entries
__device__ __forceinline__ int detect64(const int* __restrict__ ei) {
    int lane = threadIdx.x & 63;
    int hi = ei[lane * 2 + 1];
    return __any(hi != 0) ? 0 : 1;
}

// ---------------- graph build ----------------

// count degrees (edge blocks) + convert all weights to hi/lo bf16 planes (extra blocks)
__global__ void count_convert_kernel(const int* __restrict__ ei, int* __restrict__ deg,
                                     int E, int EB,
                                     const float* __restrict__ W1, const float* __restrict__ Wh,
                                     const float* __restrict__ Wf,
                                     unsigned short* __restrict__ Wc1, unsigned short* __restrict__ Wch0,
                                     unsigned short* __restrict__ Wch1, unsigned short* __restrict__ Wcf) {
    if (blockIdx.x < EB) {
        int is64 = detect64(ei);
        int e = blockIdx.x * 256 + threadIdx.x;
        if (e < E) {
            int d = load_idx(ei, (long long)E + e, is64);   // dst
            atomicAdd(&deg[d], 1);
        }
    } else {
        int idx = (blockIdx.x - EB) * 256 + threadIdx.x;    // 0 .. 55295
        if (idx < 49152) {
            int which = idx >> 14;                           // 0,1,2
            int j = idx & 16383;
            int nn = j >> 7, k = j & 127;
            const float* W = (which == 0) ? W1 : (which == 1) ? Wh : Wh + 16384;
            unsigned short* o = (which == 0) ? Wc1 : (which == 1) ? Wch0 : Wch1;
            float v = W[k * 128 + nn];
            unsigned short h = f2bf(v);
            o[j] = h;
            o[16384 + j] = f2bf(v - bf2f(h));
        } else if (idx < 49152 + 6144) {
            int j = idx - 49152;
            int nn = j >> 7, k = j & 127;
            float v = (nn < NC) ? Wf[k * NC + nn] : 0.f;
            unsigned short h = f2bf(v);
            Wcf[j] = h;
            Wcf[6144 + j] = f2bf(v - bf2f(h));
        }
    }
}

// phase 1: per-block (512) sums of deg
__global__ void scan1_kernel(const int* __restrict__ deg, int* __restrict__ bsum, int m) {
    int i = blockIdx.x * 512 + threadIdx.x;
    int v = (i < m) ? deg[i] : 0;
    #pragma unroll
    for (int off = 32; off; off >>= 1) v += __shfl_down(v, off, 64);
    __shared__ int ws[8];
    if ((threadIdx.x & 63) == 0) ws[threadIdx.x >> 6] = v;
    __syncthreads();
    if (threadIdx.x == 0) {
        int s = 0;
        #pragma unroll
        for (int j = 0; j < 8; ++j) s += ws[j];
        bsum[blockIdx.x] = s;
    }
}

// phase 2: inline prefix over bsum + local scan + emit rowptr/fill/dinv
__global__ void scan3_kernel(const int* __restrict__ deg, const int* __restrict__ bsum,
                             int* __restrict__ rowptr, int* __restrict__ fill,
                             float* __restrict__ dinv, int n, int E, int nb) {
    int t = threadIdx.x;                       // 512
    int lane = t & 63, w = t >> 6;
    int pv = (t < nb && t < (int)blockIdx.x) ? bsum[t] : 0;
    int rs = pv;
    #pragma unroll
    for (int off = 32; off; off >>= 1) rs += __shfl_down(rs, off, 64);
    __shared__ int red[8];
    if (lane == 0) red[w] = rs;
    __syncthreads();
    int base = 0;
    #pragma unroll
    for (int j = 0; j < 8; ++j) base += red[j];
    __syncthreads();

    int i = blockIdx.x * 512 + t;
    int v = (i < n) ? deg[i] : 0;
    int s = v;
    #pragma unroll
    for (int off = 1; off < 64; off <<= 1) {
        int x = __shfl_up(s, off, 64);
        if (lane >= off) s += x;
    }
    __shared__ int wsum[8];
    if (lane == 63) wsum[w] = s;
    __syncthreads();
    int wbase = 0;
    #pragma unroll
    for (int j = 0; j < 8; ++j) if (j < w) wbase += wsum[j];
    int excl = base + wbase + s - v;
    if (i < n) {
        rowptr[i] = excl;
        fill[i]   = excl;
        dinv[i]   = rsqrtf((float)(v + 1));   // +1 self loop
    }
    if (i == 0) rowptr[n] = E;
}

// scatter edge -> CSR, packing {src, dinv[src]}
__global__ void scatter_kernel(const int* __restrict__ ei, int* __restrict__ fill,
                               const float* __restrict__ dinv, int2* __restrict__ col2, int E) {
    int is64 = detect64(ei);
    int e = blockIdx.x * 256 + threadIdx.x;
    if (e >= E) return;
    int s = load_idx(ei, (long long)e, is64);
    int d = load_idx(ei, (long long)E + e, is64);
    int pos = atomicAdd(&fill[d], 1);
    col2[pos] = make_int2(s, __float_as_int(dinv[s]));
}

// ---------------- fused layer with in-block work stealing ----------------
// 512 threads = 8 waves, 32-node tile. Waves claim PAIRS of rows (2 nodes, the
// r5-proven 32-lane/node gather) from an LDS counter: block gather time ~
// total/8 + one-pair tail, i.e. sort-level balance with no global sort, no
// perm, natural node order. One __syncthreads, then M=32 MFMA epilogue
// (wave -> 16-col strip x both row-tiles, W frags loaded once, reused 2x).
__launch_bounds__(512)
__global__ void fused_steal_kernel(const float4* __restrict__ h4,
                                   const unsigned short* __restrict__ Wcvt,  // [128n][128k] hi,lo
                                   const float* __restrict__ bias,
                                   const float* __restrict__ dinv,
                                   const int* __restrict__ rowptr, const int2* __restrict__ col2,
                                   float* __restrict__ out, int n) {
    __shared__ unsigned short Ah[32 * 128];    // 8KB swizzled [row][k]
    __shared__ unsigned short Al[32 * 128];    // 8KB
    __shared__ int pnodes[32];
    __shared__ int cnt;
    int t = threadIdx.x;
    int wv = t >> 6, l = t & 63;
    int p = l >> 5, li = l & 31;               // pair slot, lane-in-node
    if (t == 0) cnt = 8;
    __syncthreads();

    int base = blockIdx.x * 32;
    int pr = wv;                               // pre-assigned pair
    while (pr < 16) {
        int row = 2 * pr + p;
        int node = base + row;
        int nd = (node < n) ? node : (n - 1);
        if (li == 0) pnodes[row] = (node < n) ? node : -1;
        float dn = dinv[nd];
        size_t rowbase = (size_t)nd * 32;
        float4 hv = h4[rowbase + li];
        float4 acc;
        acc.x = hv.x * dn; acc.y = hv.y * dn; acc.z = hv.z * dn; acc.w = hv.w * dn;
        int e = rowptr[nd], e1 = rowptr[nd + 1];
        for (; e + 8 <= e1; e += 8) {
            int2 c[8];
            #pragma unroll
            for (int q = 0; q < 8; ++q) c[q] = col2[e + q];
            float4 v[8];
            #pragma unroll
            for (int q = 0; q < 8; ++q) v[q] = h4[(size_t)c[q].x * 32 + li];
            #pragma unroll
            for (int q = 0; q < 8; ++q) {
                float ds = __int_as_float(c[q].y);
                acc.x += v[q].x * ds; acc.y += v[q].y * ds;
                acc.z += v[q].z * ds; acc.w += v[q].w * ds;
            }
        }
        for (; e + 4 <= e1; e += 4) {
            int2 c[4];
            #pragma unroll
            for (int q = 0; q < 4; ++q) c[q] = col2[e + q];
            float4 v[4];
            #pragma unroll
            for (int q = 0; q < 4; ++q) v[q] = h4[(size_t)c[q].x * 32 + li];
            #pragma unroll
            for (int q = 0; q < 4; ++q) {
                float ds = __int_as_float(c[q].y);
                acc.x += v[q].x * ds; acc.y += v[q].y * ds;
                acc.z += v[q].z * ds; acc.w += v[q].w * ds;
            }
        }
        for (; e < e1; ++e) {
            int2 c = col2[e];
            float ds = __int_as_float(c.y);
            float4 v = h4[(size_t)c.x * 32 + li];
            acc.x += v.x * ds; acc.y += v.y * ds; acc.z += v.z * ds; acc.w += v.w * ds;
        }
        acc.x *= dn; acc.y *= dn; acc.z *= dn; acc.w *= dn;   // bias after transform

        // split & stage row (bijective in-row swizzle)
        ushort4 hi, lo;
        hi.x = f2bf(acc.x); lo.x = f2bf(acc.x - bf2f(hi.x));
        hi.y = f2bf(acc.y); lo.y = f2bf(acc.y - bf2f(hi.y));
        hi.z = f2bf(acc.z); lo.z = f2bf(acc.z - bf2f(hi.z));
        hi.w = f2bf(acc.w); lo.w = f2bf(acc.w - bf2f(hi.w));
        int off = (row << 8) + ((li << 3) ^ ((row & 7) << 4));
        *(ushort4*)((char*)Ah + off) = hi;
        *(ushort4*)((char*)Al + off) = lo;

        // claim next pair
        int nxt;
        if (l == 0) nxt = atomicAdd(&cnt, 1);
        nxt = __shfl(nxt, 0);
        pr = nxt;
    }
    __syncthreads();

    // MFMA: wave wv owns 16-col strip wv, both 16-row tiles
    int lr = l & 15, lh = l >> 4;
    const unsigned short* Whi = Wcvt;
    const unsigned short* Wlo = Wcvt + 128 * 128;
    int col = wv * 16 + lr;
    short8v bh[4], bl[4];
    #pragma unroll
    for (int ks = 0; ks < 4; ++ks) {
        bh[ks] = *(const short8v*)&Whi[col * 128 + ks * 32 + lh * 8];
        bl[ks] = *(const short8v*)&Wlo[col * 128 + ks * 32 + lh * 8];
    }
    float bv = bias[col];
    #pragma unroll
    for (int rt = 0; rt < 2; ++rt) {
        f32x4 o = (f32x4){0.f, 0.f, 0.f, 0.f};
        #pragma unroll
        for (int ks = 0; ks < 4; ++ks) {
            int arow = rt * 16 + lr;
            int aoff = (arow << 8) + (((ks << 6) + (lh << 4)) ^ ((arow & 7) << 4));
            short8v ah = *(short8v*)((char*)Ah + aoff);
            short8v al = *(short8v*)((char*)Al + aoff);
            o = __builtin_amdgcn_mfma_f32_16x16x32_bf16(ah, bh[ks], o, 0, 0, 0);
            o = __builtin_amdgcn_mfma_f32_16x16x32_bf16(ah, bl[ks], o, 0, 0, 0);
            o = __builtin_amdgcn_mfma_f32_16x16x32_bf16(al, bh[ks], o, 0, 0, 0);
        }
        #pragma unroll
        for (int r = 0; r < 4; ++r) {
            int prow = pnodes[rt * 16 + lh * 4 + r];   // D layout: row=(lane>>4)*4+r
            if (prow >= 0) out[(size_t)prow * 128 + col] = fmaxf(o[r] + bv, 0.f);
        }
    }
}

// ---------------- MFMA final layer  C[M x 40] = A[M x 128] @ Wf + bf ----------------
__launch_bounds__(256)
__global__ void final_mfma_kernel(const float* __restrict__ A, const unsigned short* __restrict__ Wcvt,
                                  const float* __restrict__ bf, float* __restrict__ C, int M) {
    __shared__ unsigned short Ah[64 * 128];
    __shared__ unsigned short Al[64 * 128];
    int t = threadIdx.x;
    int l = t & 63, w = t >> 6;
    int lr = l & 15, lh = l >> 4;

    const unsigned short* Whi = Wcvt;            // [48n][128k]
    const unsigned short* Wlo = Wcvt + 48 * 128;
    short8v bhi[3][4], blo[3][4];
    #pragma unroll
    for (int nt = 0; nt < 3; ++nt) {
        int n = nt * 16 + lr;
        #pragma unroll
        for (int ks = 0; ks < 4; ++ks) {
            bhi[nt][ks] = *(const short8v*)&Whi[n * 128 + ks * 32 + lh * 8];
            blo[nt][ks] = *(const short8v*)&Wlo[n * 128 + ks * 32 + lh * 8];
        }
    }

    int row0 = blockIdx.x * 64;
    #pragma unroll
    for (int c = 0; c < 4; ++c) {
        int chunk = c * 256 + t;
        int r  = chunk >> 4;
        int kc = chunk & 15;
        int gr = row0 + r; if (gr >= M) gr = M - 1;
        float4 a0 = *(const float4*)&A[(size_t)gr * 128 + kc * 8];
        float4 a1 = *(const float4*)&A[(size_t)gr * 128 + kc * 8 + 4];
        float av[8] = {a0.x, a0.y, a0.z, a0.w, a1.x, a1.y, a1.z, a1.w};
        short8v hv, lv;
        #pragma unroll
        for (int j = 0; j < 8; ++j) {
            unsigned short hi = f2bf(av[j]);
            hv[j] = (short)hi;
            lv[j] = (short)f2bf(av[j] - bf2f(hi));
        }
        int off = (r << 8) + ((kc << 4) ^ ((r & 7) << 4));
        *(short8v*)((char*)Ah + off) = hv;
        *(short8v*)((char*)Al + off) = lv;
    }
    __syncthreads();

    f32x4 acc[3];
    #pragma unroll
    for (int nt = 0; nt < 3; ++nt) acc[nt] = (f32x4){0.f, 0.f, 0.f, 0.f};
    int row = w * 16 + lr;
    #pragma unroll
    for (int ks = 0; ks < 4; ++ks) {
        int off = (row << 8) + (((ks << 6) + (lh << 4)) ^ ((row & 7) << 4));
        short8v ah = *(short8v*)((char*)Ah + off);
        short8v al = *(short8v*)((char*)Al + off);
        #pragma unroll
        for (int nt = 0; nt < 3; ++nt) {
            acc[nt] = __builtin_amdgcn_mfma_f32_16x16x32_bf16(ah, bhi[nt][ks], acc[nt], 0, 0, 0);
            acc[nt] = __builtin_amdgcn_mfma_f32_16x16x32_bf16(ah, blo[nt][ks], acc[nt], 0, 0, 0);
            acc[nt] = __builtin_amdgcn_mfma_f32_16x16x32_bf16(al, bhi[nt][ks], acc[nt], 0, 0, 0);
        }
    }
    #pragma unroll
    for (int nt = 0; nt < 3; ++nt) {
        int col = nt * 16 + lr;
        #pragma unroll
        for (int r = 0; r < 4; ++r) {
            int ro = row0 + w * 16 + lh * 4 + r;
            if (col < NC && ro < M) C[(size_t)ro * NC + col] = acc[nt][r] + bf[col];
        }
    }
}

extern "C" void kernel_launch(void* const* d_in, const int* in_sizes, int n_in,
                              void* d_out, int out_size, void* d_ws, size_t ws_size,
                              hipStream_t stream) {
    const float* x  = (const float*)d_in[0];
    const int*   ei = (const int*)d_in[1];
    const float* W1 = (const float*)d_in[2];
    const float* b1 = (const float*)d_in[3];
    const float* Wh = (const float*)d_in[4];
    const float* bh = (const float*)d_in[5];
    const float* Wf = (const float*)d_in[6];
    const float* bf = (const float*)d_in[7];
    float* out = (float*)d_out;

    int n = in_sizes[0] / D;    // 50000
    int E = in_sizes[1] / 2;    // 800000

    char* ws = (char*)d_ws;
    size_t off = 0;
    auto alloc = [&](size_t bytes) {
        void* p = ws + off;
        off = (off + bytes + 255) & ~(size_t)255;
        return p;
    };
    float* B0     = (float*)alloc((size_t)n * D * 4);
    float* B1     = (float*)alloc((size_t)n * D * 4);
    int*   deg    = (int*)alloc((size_t)n * 4);
    int*   rowptr = (int*)alloc((size_t)(n + 1) * 4);
    int*   fill   = (int*)alloc((size_t)n * 4);
    int2*  col2   = (int2*)alloc((size_t)E * 8);
    float* dinv   = (float*)alloc((size_t)n * 4);
    int*   bsum   = (int*)alloc(1024 * 4);
    unsigned short* Wc1  = (unsigned short*)alloc(2 * 128 * 128 * 2);
    unsigned short* Wch0 = (unsigned short*)alloc(2 * 128 * 128 * 2);
    unsigned short* Wch1 = (unsigned short*)alloc(2 * 128 * 128 * 2);
    unsigned short* Wcf  = (unsigned short*)alloc(2 * 48 * 128 * 2);

    int EB = (E + 255) / 256;             // edge blocks
    int CB = (49152 + 6144 + 255) / 256;  // convert blocks
    int nb = (n + 511) / 512;             // 98

    hipMemsetAsync(deg, 0, (size_t)n * 4, stream);
    count_convert_kernel<<<EB + CB, 256, 0, stream>>>(ei, deg, E, EB, W1, Wh, Wf, Wc1, Wch0, Wch1, Wcf);
    scan1_kernel<<<nb, 512, 0, stream>>>(deg, bsum, n);
    scan3_kernel<<<nb, 512, 0, stream>>>(deg, bsum, rowptr, fill, dinv, n, E, nb);
    scatter_kernel<<<EB, 256, 0, stream>>>(ei, fill, dinv, col2, E);

    int fgrid = (n + 31) / 32;            // 32-node tiles, 8 waves/block

    fused_steal_kernel<<<fgrid, 512, 0, stream>>>((const float4*)x, Wc1, b1, dinv, rowptr, col2, B0, n);
    fused_steal_kernel<<<fgrid, 512, 0, stream>>>((const float4*)B0, Wch0, bh, dinv, rowptr, col2, B1, n);
    fused_steal_kernel<<<fgrid, 512, 0, stream>>>((const float4*)B1, Wch1, bh + D, dinv, rowptr, col2, B0, n);
    final_mfma_kernel<<<(n + 63) / 64, 256, 0, stream>>>(B0, Wcf, bf, out, n);
}